// Round 5
// baseline (412.686 us; speedup 1.0000x reference)
//
#include <hip/hip_runtime.h>
#include <hip/hip_bf16.h>

// Problem: B=2, S=2048, D=1024, H=16, DK=64
// out = concat_heads(softmax(mask(qk^T))v) @ Wu + bu
// Harness dtypes (R3/R4 findings): ALL float tensors are FLOAT32 (per the
// reference, which is pure jnp.float32); mask is int32; OUTPUT is FLOAT32
// (d_out holds the reference's output dtype -> float*). R4's 0.378 error was
// bf16 output read as fp32 (fp32[i] ~ bf16[2i+1] + zero tail) — exact match.
//
// Internal workspace (q/k/v projections, attn output) is bf16 — we own it.
// Softmax is max-free and finite by construction: p = exp(min(s,30))*maskbit.

typedef __bf16 bf16_t;
typedef __attribute__((ext_vector_type(8))) __bf16 bf16x8;
typedef __attribute__((ext_vector_type(4))) float f32x4;

#define B_ 2
#define S_ 2048
#define D_ 1024
#define H_ 16
#define DK_ 64

static __device__ __forceinline__ f32x4 mfma16(bf16x8 a, bf16x8 b, f32x4 c) {
  return __builtin_amdgcn_mfma_f32_16x16x32_bf16(a, b, c, 0, 0, 0);
}

// ---------------------------------------------------------------------------
// Pack mask [B,S,S] int32 -> bitfield: word w covers flat elements
// w*32 .. w*32+31; bit i = (mask != 0).
// ---------------------------------------------------------------------------
__global__ __launch_bounds__(256) void mask_pack(const int* __restrict__ mask,
                                                 unsigned int* __restrict__ bits) {
  int w = blockIdx.x * 256 + threadIdx.x;  // 0 .. B*S*S/32-1
  const int4* p = (const int4*)(mask + (size_t)w * 32);
  unsigned int v = 0;
#pragma unroll
  for (int i = 0; i < 8; ++i) {
    int4 m4 = p[i];
    v |= (m4.x != 0 ? 1u : 0u) << (i * 4 + 0);
    v |= (m4.y != 0 ? 1u : 0u) << (i * 4 + 1);
    v |= (m4.z != 0 ? 1u : 0u) << (i * 4 + 2);
    v |= (m4.w != 0 ? 1u : 0u) << (i * 4 + 3);
  }
  bits[w] = v;
}

// ---------------------------------------------------------------------------
// Per-head projection: out[b,h,s,k] = scale * sum_d X[b,s,d] * W[h,d,k]
// X fp32 [B,S,D], W fp32 [H,D,DK] -> bf16 in LDS -> MFMA -> bf16 out.
// Block: 64 rows x 64 cols (= one head's DK). 4 waves, 16 rows each.
// ---------------------------------------------------------------------------
__global__ __launch_bounds__(256) void qkv_proj(const float* __restrict__ X,
                                                const float* __restrict__ W,
                                                bf16_t* __restrict__ out,
                                                float scale) {
  __shared__ __align__(16) bf16_t Xs[64][72];   // [row][k]  (+8 pad)
  __shared__ __align__(16) bf16_t Wts[64][72];  // [n][k] transposed

  const int tid = threadIdx.x;
  const int lane = tid & 63, wave = tid >> 6;
  const int l = lane & 15, quad = lane >> 4;
  const int row0 = blockIdx.x * 64;
  const int h = blockIdx.y;

  const f32x4 zero = {0.f, 0.f, 0.f, 0.f};
  f32x4 acc[4] = {zero, zero, zero, zero};

  for (int k0 = 0; k0 < D_; k0 += 64) {
    __syncthreads();
    // stage X tile: fp32 float4 loads -> bf16 LDS
#pragma unroll
    for (int it = 0; it < 4; ++it) {
      int t = tid + it * 256;          // 0..1023
      int r = t >> 4, c = (t & 15) * 4;
      float4 x4 = *(const float4*)(X + (size_t)(row0 + r) * D_ + k0 + c);
      bf16_t* dst = &Xs[r][c];
      dst[0] = (bf16_t)x4.x; dst[1] = (bf16_t)x4.y;
      dst[2] = (bf16_t)x4.z; dst[3] = (bf16_t)x4.w;
    }
    // stage W tile transposed: fp32 reads, bf16 scatter to [n][k]
    {
      int kk = tid >> 2;            // k within tile, 0..63
      int n0 = (tid & 3) * 16;      // col group
      const float* wp = W + (size_t)h * D_ * DK_ + (size_t)(k0 + kk) * DK_ + n0;
#pragma unroll
      for (int g = 0; g < 4; ++g) {
        float4 w4 = *(const float4*)(wp + g * 4);
        Wts[n0 + g * 4 + 0][kk] = (bf16_t)w4.x;
        Wts[n0 + g * 4 + 1][kk] = (bf16_t)w4.y;
        Wts[n0 + g * 4 + 2][kk] = (bf16_t)w4.z;
        Wts[n0 + g * 4 + 3][kk] = (bf16_t)w4.w;
      }
    }
    __syncthreads();

    bf16x8 a0 = *(const bf16x8*)&Xs[wave * 16 + l][quad * 8];
    bf16x8 a1 = *(const bf16x8*)&Xs[wave * 16 + l][32 + quad * 8];
#pragma unroll
    for (int nt = 0; nt < 4; ++nt) {
      bf16x8 b0 = *(const bf16x8*)&Wts[nt * 16 + l][quad * 8];
      bf16x8 b1 = *(const bf16x8*)&Wts[nt * 16 + l][32 + quad * 8];
      acc[nt] = mfma16(a0, b0, acc[nt]);
      acc[nt] = mfma16(a1, b1, acc[nt]);
    }
  }

  // epilogue: C layout row = quad*4+reg, col = l. out layout [B,H,S,DK].
#pragma unroll
  for (int nt = 0; nt < 4; ++nt) {
#pragma unroll
    for (int reg = 0; reg < 4; ++reg) {
      int grow = row0 + wave * 16 + quad * 4 + reg;  // 0..4095 = b*S + s
      int bb = grow >> 11, ss = grow & (S_ - 1);
      out[(((size_t)bb * H_ + h) * S_ + ss) * DK_ + nt * 16 + l] =
          (bf16_t)(acc[nt][reg] * scale);
    }
  }
}

// ---------------------------------------------------------------------------
// Flash-style attention, max-free unnormalized softmax. Block = (64 q-rows,
// head, batch); 4 waves, 16 query rows each; 64-wide K/V tiles. All bf16 in.
// ---------------------------------------------------------------------------
__global__ __launch_bounds__(256) void attn_kernel(
    const bf16_t* __restrict__ Q, const bf16_t* __restrict__ K,
    const bf16_t* __restrict__ V, const unsigned int* __restrict__ mbits,
    bf16_t* __restrict__ out) {
  __shared__ __align__(16) bf16_t Ks[64][72];       // [t][c]
  __shared__ __align__(16) bf16_t Vts[64][72];      // [c][t] transposed
  __shared__ __align__(16) bf16_t Ps[4][16][72];    // per-wave P transpose buf

  const int tid = threadIdx.x;
  const int lane = tid & 63, wave = tid >> 6;
  const int l = lane & 15, quad = lane >> 4;
  const int qt = blockIdx.x, h = blockIdx.y, b = blockIdx.z;

  const size_t bh = ((size_t)b * H_ + h) * S_;
  const bf16_t* Qb = Q + bh * DK_;
  const bf16_t* Kb = K + bh * DK_;
  const bf16_t* Vb = V + bh * DK_;

  const int qrow = qt * 64 + wave * 16 + l;
  bf16x8 aq0 = *(const bf16x8*)(Qb + (size_t)qrow * DK_ + quad * 8);
  bf16x8 aq1 = *(const bf16x8*)(Qb + (size_t)qrow * DK_ + 32 + quad * 8);

  const f32x4 zero = {0.f, 0.f, 0.f, 0.f};
  f32x4 o[4] = {zero, zero, zero, zero};
  float lpart[4] = {0.f, 0.f, 0.f, 0.f};  // per-lane partial row sums

  const unsigned int* mrow[4];
#pragma unroll
  for (int reg = 0; reg < 4; ++reg) {
    int srow = qt * 64 + wave * 16 + quad * 4 + reg;
    mrow[reg] = mbits + ((size_t)b * S_ + srow) * (S_ / 32);
  }

  for (int t0 = 0; t0 < S_; t0 += 64) {
    __syncthreads();
    // stage K tile [t][c]
#pragma unroll
    for (int it = 0; it < 2; ++it) {
      int t = tid + it * 256;
      int r = t >> 3, c = (t & 7) * 8;
      *(bf16x8*)&Ks[r][c] = *(const bf16x8*)(Kb + (size_t)(t0 + r) * DK_ + c);
    }
    // stage V tile transposed [c][t]
    {
      int tr = tid >> 2, n0 = (tid & 3) * 16;
      const bf16_t* vp = Vb + (size_t)(t0 + tr) * DK_ + n0;
      bf16x8 v0 = *(const bf16x8*)vp;
      bf16x8 v1 = *(const bf16x8*)(vp + 8);
#pragma unroll
      for (int i = 0; i < 8; ++i) Vts[n0 + i][tr] = v0[i];
#pragma unroll
      for (int i = 0; i < 8; ++i) Vts[n0 + 8 + i][tr] = v1[i];
    }
    __syncthreads();

    // scores: 16 x 64 per wave, C layout (row=quad*4+reg, col=ts*16+l)
    f32x4 sf[4];
#pragma unroll
    for (int ts = 0; ts < 4; ++ts) {
      bf16x8 bk0 = *(const bf16x8*)&Ks[ts * 16 + l][quad * 8];
      bf16x8 bk1 = *(const bf16x8*)&Ks[ts * 16 + l][32 + quad * 8];
      f32x4 c = zero;
      c = mfma16(aq0, bk0, c);
      c = mfma16(aq1, bk1, c);
      sf[ts] = c;
    }

    // p = exp(min(s,30)) * maskbit  — all finite, masked exactly 0
#pragma unroll
    for (int reg = 0; reg < 4; ++reg) {
      unsigned int w0 = mrow[reg][(t0 >> 5) + 0];
      unsigned int w1 = mrow[reg][(t0 >> 5) + 1];
#pragma unroll
      for (int ts = 0; ts < 4; ++ts) {
        unsigned int w = (ts < 2) ? w0 : w1;
        int bit = (ts & 1) * 16 + l;
        float keep = (float)((w >> bit) & 1u);
        float p = __expf(fminf(sf[ts][reg], 30.0f)) * keep;
        lpart[reg] += p;
        Ps[wave][quad * 4 + reg][ts * 16 + l] = (bf16_t)p;
      }
    }

    // P: C layout -> LDS -> A layout (per-wave buffer; DS ops in-order/wave)
    bf16x8 ap0 = *(const bf16x8*)&Ps[wave][l][quad * 8];
    bf16x8 ap1 = *(const bf16x8*)&Ps[wave][l][32 + quad * 8];
#pragma unroll
    for (int nt = 0; nt < 4; ++nt) {
      bf16x8 bv0 = *(const bf16x8*)&Vts[nt * 16 + l][quad * 8];
      bf16x8 bv1 = *(const bf16x8*)&Vts[nt * 16 + l][32 + quad * 8];
      o[nt] = mfma16(ap0, bv0, o[nt]);
      o[nt] = mfma16(ap1, bv1, o[nt]);
    }
  }

  // epilogue: single reduction of row sums, guarded divide, write [B,S,H*DK]
#pragma unroll
  for (int reg = 0; reg < 4; ++reg) {
    float rsum = lpart[reg];
#pragma unroll
    for (int m = 1; m < 16; m <<= 1) rsum += __shfl_xor(rsum, m);
    float inv = (rsum > 0.f) ? (1.f / rsum) : 0.f;
    int srow = qt * 64 + wave * 16 + quad * 4 + reg;
    bf16_t* op = out + ((size_t)b * S_ + srow) * D_ + h * DK_;
#pragma unroll
    for (int nt = 0; nt < 4; ++nt)
      op[nt * 16 + l] = (bf16_t)(o[nt][reg] * inv);
  }
}

// ---------------------------------------------------------------------------
// Output projection: out[r, e] = sum_d A[r,d] * Wu[d,e] + bu[e]
// A bf16 workspace; Wu/bu fp32; OUT FP32 (the harness's d_out dtype).
// ---------------------------------------------------------------------------
__global__ __launch_bounds__(256) void out_proj(const bf16_t* __restrict__ Xa,
                                                const float* __restrict__ Wu,
                                                const float* __restrict__ bu,
                                                float* __restrict__ out) {
  __shared__ __align__(16) bf16_t Xs[64][72];
  __shared__ __align__(16) bf16_t Wts[64][72];

  const int tid = threadIdx.x;
  const int lane = tid & 63, wave = tid >> 6;
  const int l = lane & 15, quad = lane >> 4;
  const int row0 = blockIdx.x * 64;
  const int col0 = blockIdx.y * 64;

  const f32x4 zero = {0.f, 0.f, 0.f, 0.f};
  f32x4 acc[4] = {zero, zero, zero, zero};

  for (int k0 = 0; k0 < D_; k0 += 64) {
    __syncthreads();
    // stage A tile (bf16 workspace, 16B vector loads)
#pragma unroll
    for (int it = 0; it < 2; ++it) {
      int t = tid + it * 256;
      int r = t >> 3, c = (t & 7) * 8;
      *(bf16x8*)&Xs[r][c] = *(const bf16x8*)(Xa + (size_t)(row0 + r) * D_ + k0 + c);
    }
    // stage Wu tile transposed: fp32 reads -> bf16 [n][k]
    {
      int kk = tid >> 2;
      int n0 = (tid & 3) * 16;
      const float* wp = Wu + (size_t)(k0 + kk) * D_ + col0 + n0;
#pragma unroll
      for (int g = 0; g < 4; ++g) {
        float4 w4 = *(const float4*)(wp + g * 4);
        Wts[n0 + g * 4 + 0][kk] = (bf16_t)w4.x;
        Wts[n0 + g * 4 + 1][kk] = (bf16_t)w4.y;
        Wts[n0 + g * 4 + 2][kk] = (bf16_t)w4.z;
        Wts[n0 + g * 4 + 3][kk] = (bf16_t)w4.w;
      }
    }
    __syncthreads();

    bf16x8 a0 = *(const bf16x8*)&Xs[wave * 16 + l][quad * 8];
    bf16x8 a1 = *(const bf16x8*)&Xs[wave * 16 + l][32 + quad * 8];
#pragma unroll
    for (int nt = 0; nt < 4; ++nt) {
      bf16x8 b0 = *(const bf16x8*)&Wts[nt * 16 + l][quad * 8];
      bf16x8 b1 = *(const bf16x8*)&Wts[nt * 16 + l][32 + quad * 8];
      acc[nt] = mfma16(a0, b0, acc[nt]);
      acc[nt] = mfma16(a1, b1, acc[nt]);
    }
  }

#pragma unroll
  for (int nt = 0; nt < 4; ++nt) {
#pragma unroll
    for (int reg = 0; reg < 4; ++reg) {
      int grow = row0 + wave * 16 + quad * 4 + reg;
      int col = col0 + nt * 16 + l;
      out[(size_t)grow * D_ + col] = acc[nt][reg] + bu[col];
    }
  }
}

// ---------------------------------------------------------------------------
extern "C" void kernel_launch(void* const* d_in, const int* in_sizes, int n_in,
                              void* d_out, int out_size, void* d_ws, size_t ws_size,
                              hipStream_t stream) {
  const float* q_in = (const float*)d_in[0];
  const float* k_in = (const float*)d_in[1];
  const float* v_in = (const float*)d_in[2];
  const int* mask = (const int*)d_in[3];
  const float* Wq = (const float*)d_in[4];
  const float* Wk = (const float*)d_in[5];
  const float* Wv = (const float*)d_in[6];
  const float* Wu = (const float*)d_in[7];
  const float* bu = (const float*)d_in[8];
  float* outp = (float*)d_out;  // reference output dtype = float32

  const size_t nqkv = (size_t)B_ * H_ * S_ * DK_;   // 4 Mi elements
  bf16_t* qb = (bf16_t*)d_ws;
  bf16_t* kb = qb + nqkv;
  bf16_t* vb = kb + nqkv;
  bf16_t* ab = vb + nqkv;                            // [B,S,D] attn output
  unsigned int* mb = (unsigned int*)(ab + (size_t)B_ * S_ * D_);

  const float qkscale = 0.35355339059327373f;  // 1 / 64^0.25

  dim3 blk(256);
  mask_pack<<<dim3((B_ * S_ * S_ / 32) / 256), blk, 0, stream>>>(mask, mb);
  qkv_proj<<<dim3(64, H_), blk, 0, stream>>>(q_in, Wq, qb, qkscale);
  qkv_proj<<<dim3(64, H_), blk, 0, stream>>>(k_in, Wk, kb, qkscale);
  qkv_proj<<<dim3(64, H_), blk, 0, stream>>>(v_in, Wv, vb, 1.0f);
  attn_kernel<<<dim3(S_ / 64, H_, B_), blk, 0, stream>>>(qb, kb, vb, mb, ab);
  out_proj<<<dim3(64, D_ / 64), blk, 0, stream>>>(ab, Wu, bu, outp);
}

// Round 6
// 335.973 us; speedup vs baseline: 1.2283x; 1.2283x over previous
//
#include <hip/hip_runtime.h>
#include <hip/hip_bf16.h>

// Problem: B=2, S=2048, D=1024, H=16, DK=64
// out = concat_heads(softmax(mask(qk^T))v) @ Wu + bu
// Inputs fp32 (mask int32), output fp32. Internal: bf16.
//
// R5 structure:
//   1. cvt_x: q/k/v fp32 -> bf16 [4096,1024]
//   2. wtrans: Wq/Wk/Wv [H,D,DK] + Wu [D,D] -> n-major bf16 BT[n][d]
//      (qk scale 1/DK^0.25 folded into BTq/BTk)
//   3. mask_pack -> bitfield
//   4. gemm_bt<bf16 out> batched z=3: q/k/v projections (128x128 tiles,
//      global_load_lds width-16 staging, m97 pattern)
//   5. attn: flash-style, max-free finite softmax, conflict-free staging
//   6. gemm_bt<f32 out + bias>: out = ab @ Wu + bu
// Workspace: 6*8MB (x+proj) + 4*2MB (BT) + 1MB (mask bits) = 57 MB; attn
// output aliases qx (dead after step 4).

typedef __bf16 bf16_t;
typedef __attribute__((ext_vector_type(8))) __bf16 bf16x8;
typedef __attribute__((ext_vector_type(4))) float f32x4;
typedef unsigned int u32;

#define B_ 2
#define S_ 2048
#define D_ 1024
#define H_ 16
#define DK_ 64
#define NX_ (4096 * 1024)

static __device__ __forceinline__ f32x4 mfma16(bf16x8 a, bf16x8 b, f32x4 c) {
  return __builtin_amdgcn_mfma_f32_16x16x32_bf16(a, b, c, 0, 0, 0);
}

// async global->LDS, 16B per lane; lds base must be wave-uniform
static __device__ __forceinline__ void async16(const bf16_t* g, bf16_t* l) {
  __builtin_amdgcn_global_load_lds(
      (const __attribute__((address_space(1))) u32*)g,
      (__attribute__((address_space(3))) u32*)l, 16, 0, 0);
}

// ---------------------------------------------------------------------------
// q/k/v fp32 -> bf16, 8 elements/thread. grid (2048, 3)
// ---------------------------------------------------------------------------
__global__ __launch_bounds__(256) void cvt_x(const float* __restrict__ q,
                                             const float* __restrict__ k,
                                             const float* __restrict__ v,
                                             bf16_t* __restrict__ qo,
                                             bf16_t* __restrict__ ko,
                                             bf16_t* __restrict__ vo) {
  const int z = blockIdx.y;
  const float* src = (z == 0) ? q : (z == 1) ? k : v;
  bf16_t* dst = (z == 0) ? qo : (z == 1) ? ko : vo;
  size_t i = ((size_t)blockIdx.x * 256 + threadIdx.x) * 8;
  float4 a = *(const float4*)(src + i);
  float4 b = *(const float4*)(src + i + 4);
  bf16x8 o;
  o[0] = (bf16_t)a.x; o[1] = (bf16_t)a.y; o[2] = (bf16_t)a.z; o[3] = (bf16_t)a.w;
  o[4] = (bf16_t)b.x; o[5] = (bf16_t)b.y; o[6] = (bf16_t)b.z; o[7] = (bf16_t)b.w;
  *(bf16x8*)(dst + i) = o;
}

// ---------------------------------------------------------------------------
// Weight transpose -> n-major bf16. grid (16 d-tiles, 16 n-tiles, 4 tensors).
// z<3: W [H=nt][D][DK] -> BT[nt*64+k][d];  z=3: Wu [D][D] -> BT[n][d].
// ---------------------------------------------------------------------------
__global__ __launch_bounds__(256) void wtrans(
    const float* __restrict__ Wq, const float* __restrict__ Wk,
    const float* __restrict__ Wv, const float* __restrict__ Wu,
    bf16_t* __restrict__ Bq, bf16_t* __restrict__ Bk,
    bf16_t* __restrict__ Bv, bf16_t* __restrict__ Bu, float qkscale) {
  __shared__ __align__(16) bf16_t T[64][64];  // [n-in-tile][d-in-tile]
  const int z = blockIdx.z;
  const float* W = (z == 0) ? Wq : (z == 1) ? Wk : (z == 2) ? Wv : Wu;
  bf16_t* BT = (z == 0) ? Bq : (z == 1) ? Bk : (z == 2) ? Bv : Bu;
  const float scale = (z <= 1) ? qkscale : 1.0f;
  const int d0 = blockIdx.x * 64, nt = blockIdx.y;
  const int tid = threadIdx.x;
  const int r = tid & 63, g = tid >> 6;  // r = d row, g = col quarter

  const float* src = (z < 3)
      ? W + ((size_t)nt * D_ + d0 + r) * DK_ + g * 16
      : W + (size_t)(d0 + r) * D_ + nt * 64 + g * 16;
#pragma unroll
  for (int j = 0; j < 4; ++j) {
    float4 w4 = *(const float4*)(src + j * 4);
    T[g * 16 + j * 4 + 0][r] = (bf16_t)(w4.x * scale);
    T[g * 16 + j * 4 + 1][r] = (bf16_t)(w4.y * scale);
    T[g * 16 + j * 4 + 2][r] = (bf16_t)(w4.z * scale);
    T[g * 16 + j * 4 + 3][r] = (bf16_t)(w4.w * scale);
  }
  __syncthreads();
  const int orow = tid >> 3, seg = tid & 7;
#pragma unroll
  for (int p = 0; p < 2; ++p) {
    int rr = p * 32 + orow;
    *(bf16x8*)(BT + (size_t)(nt * 64 + rr) * D_ + d0 + seg * 8) =
        *(const bf16x8*)&T[rr][seg * 8];
  }
}

// ---------------------------------------------------------------------------
// Pack mask [B,S,S] int32 -> bitfield (bit = mask != 0)
// ---------------------------------------------------------------------------
__global__ __launch_bounds__(256) void mask_pack(const int* __restrict__ mask,
                                                 unsigned int* __restrict__ bits) {
  int w = blockIdx.x * 256 + threadIdx.x;
  const int4* p = (const int4*)(mask + (size_t)w * 32);
  unsigned int v = 0;
#pragma unroll
  for (int i = 0; i < 8; ++i) {
    int4 m4 = p[i];
    v |= (m4.x != 0 ? 1u : 0u) << (i * 4 + 0);
    v |= (m4.y != 0 ? 1u : 0u) << (i * 4 + 1);
    v |= (m4.z != 0 ? 1u : 0u) << (i * 4 + 2);
    v |= (m4.w != 0 ? 1u : 0u) << (i * 4 + 3);
  }
  bits[w] = v;
}

// ---------------------------------------------------------------------------
// GEMM: C[4096,1024] = A[4096,1024] @ BT[1024,1024]^T   (BT is n-major)
// 128x128 tiles, BK=64, 4 waves in 2x2, global_load_lds staging.
// BIAS_F32: fp32 out + bias; else bf16 out. z selects A/BT/C (batched qkv).
// ---------------------------------------------------------------------------
template <bool BIAS_F32>
__global__ __launch_bounds__(256) void gemm_bt(
    const bf16_t* __restrict__ A0, const bf16_t* __restrict__ A1,
    const bf16_t* __restrict__ A2, const bf16_t* __restrict__ BT0,
    const bf16_t* __restrict__ BT1, const bf16_t* __restrict__ BT2,
    void* __restrict__ C0, void* __restrict__ C1, void* __restrict__ C2,
    const float* __restrict__ bias) {
  __shared__ __align__(16) bf16_t As[128 * 64];
  __shared__ __align__(16) bf16_t Bs[128 * 64];

  const int z = blockIdx.z;
  const bf16_t* A = (z == 0) ? A0 : (z == 1) ? A1 : A2;
  const bf16_t* BT = (z == 0) ? BT0 : (z == 1) ? BT1 : BT2;
  void* C = (z == 0) ? C0 : (z == 1) ? C1 : C2;

  const int tid = threadIdx.x;
  const int lane = tid & 63, wave = tid >> 6;
  const int l = lane & 15, quad = lane >> 4;
  const int wm = wave >> 1, wn = wave & 1;
  const int row0 = blockIdx.x * 128, col0 = blockIdx.y * 128;

  const int lr = lane >> 3, lc = (lane & 7) * 8;  // staging: 8 lanes/row

  f32x4 acc[4][4];
#pragma unroll
  for (int i = 0; i < 4; ++i)
#pragma unroll
    for (int j = 0; j < 4; ++j) acc[i][j] = {0.f, 0.f, 0.f, 0.f};

  for (int k0 = 0; k0 < 1024; k0 += 64) {
    __syncthreads();
#pragma unroll
    for (int c = 0; c < 4; ++c) {
      int r = wave * 32 + c * 8;  // wave-uniform
      async16(A + (size_t)(row0 + r + lr) * 1024 + k0 + lc, As + r * 64);
      async16(BT + (size_t)(col0 + r + lr) * 1024 + k0 + lc, Bs + r * 64);
    }
    __syncthreads();  // drains vmcnt before barrier

#pragma unroll
    for (int kh = 0; kh < 2; ++kh) {
      bf16x8 af[4], bf[4];
#pragma unroll
      for (int f = 0; f < 4; ++f)
        af[f] = *(const bf16x8*)&As[(wm * 64 + f * 16 + l) * 64 + kh * 32 + quad * 8];
#pragma unroll
      for (int f = 0; f < 4; ++f)
        bf[f] = *(const bf16x8*)&Bs[(wn * 64 + f * 16 + l) * 64 + kh * 32 + quad * 8];
#pragma unroll
      for (int fm = 0; fm < 4; ++fm)
#pragma unroll
        for (int fn = 0; fn < 4; ++fn)
          acc[fm][fn] = mfma16(af[fm], bf[fn], acc[fm][fn]);
    }
  }

#pragma unroll
  for (int fm = 0; fm < 4; ++fm)
#pragma unroll
    for (int fn = 0; fn < 4; ++fn)
#pragma unroll
      for (int reg = 0; reg < 4; ++reg) {
        int row = row0 + wm * 64 + fm * 16 + quad * 4 + reg;
        int col = col0 + wn * 64 + fn * 16 + l;
        if (BIAS_F32)
          ((float*)C)[(size_t)row * 1024 + col] = acc[fm][fn][reg] + bias[col];
        else
          ((bf16_t*)C)[(size_t)row * 1024 + col] = (bf16_t)acc[fm][fn][reg];
      }
}

// ---------------------------------------------------------------------------
// Flash attention. Q/K/V in [B*S, D] bf16 (head h = cols h*64..h*64+63).
// Block = (64 q-rows, head, batch); 4 waves x 16 q-rows; 64-wide K/V tiles.
// Max-free finite softmax: p = exp(min(s,30)) * maskbit.
// ---------------------------------------------------------------------------
__global__ __launch_bounds__(256) void attn_kernel(
    const bf16_t* __restrict__ Qx, const bf16_t* __restrict__ Kx,
    const bf16_t* __restrict__ Vx, const unsigned int* __restrict__ mbits,
    bf16_t* __restrict__ out) {
  __shared__ __align__(16) bf16_t Ks[64][64];    // [t][c]
  __shared__ __align__(16) bf16_t Vts[64][64];   // [c][t]
  __shared__ __align__(16) bf16_t Ps[4][16][64]; // per-wave P transpose

  const int tid = threadIdx.x;
  const int lane = tid & 63, wave = tid >> 6;
  const int l = lane & 15, quad = lane >> 4;
  const int qt = blockIdx.x, h = blockIdx.y, b = blockIdx.z;
  const int ch = h * 64;
  const size_t rb = (size_t)b * S_;

  const int qrow = qt * 64 + wave * 16 + l;
  bf16x8 aq0 = *(const bf16x8*)(Qx + (rb + qrow) * D_ + ch + quad * 8);
  bf16x8 aq1 = *(const bf16x8*)(Qx + (rb + qrow) * D_ + ch + 32 + quad * 8);

  const f32x4 zero = {0.f, 0.f, 0.f, 0.f};
  f32x4 o[4] = {zero, zero, zero, zero};
  float lpart[4] = {0.f, 0.f, 0.f, 0.f};

  const unsigned int* mrow[4];
#pragma unroll
  for (int reg = 0; reg < 4; ++reg) {
    int srow = qt * 64 + wave * 16 + quad * 4 + reg;
    mrow[reg] = mbits + ((size_t)b * S_ + srow) * (S_ / 32);
  }

  const int tr = tid & 63, g = tid >> 6;  // V-transpose staging coords

  for (int t0 = 0; t0 < S_; t0 += 64) {
    __syncthreads();
    // K tile [t][c]: 8 lanes per 128B row, b128 writes, conflict-free
#pragma unroll
    for (int it = 0; it < 2; ++it) {
      int t = tid + it * 256;
      int r = t >> 3, c = (t & 7) * 8;
      *(bf16x8*)&Ks[r][c] = *(const bf16x8*)(Kx + (rb + t0 + r) * D_ + ch + c);
    }
    // V tile transposed [c][t]: lane-adjacent rows -> conflict-free b16 writes
    {
      const bf16_t* vp = Vx + (rb + t0 + tr) * D_ + ch + g * 16;
      bf16x8 v0 = *(const bf16x8*)vp;
      bf16x8 v1 = *(const bf16x8*)(vp + 8);
#pragma unroll
      for (int i = 0; i < 8; ++i) Vts[g * 16 + i][tr] = v0[i];
#pragma unroll
      for (int i = 0; i < 8; ++i) Vts[g * 16 + 8 + i][tr] = v1[i];
    }
    __syncthreads();

    // scores: 16x64 per wave, C layout (row=quad*4+reg, col=ts*16+l)
    f32x4 sf[4];
#pragma unroll
    for (int ts = 0; ts < 4; ++ts) {
      bf16x8 bk0 = *(const bf16x8*)&Ks[ts * 16 + l][quad * 8];
      bf16x8 bk1 = *(const bf16x8*)&Ks[ts * 16 + l][32 + quad * 8];
      f32x4 c = zero;
      c = mfma16(aq0, bk0, c);
      c = mfma16(aq1, bk1, c);
      sf[ts] = c;
    }

    // p = exp(min(s,30)) * maskbit — finite by construction
#pragma unroll
    for (int reg = 0; reg < 4; ++reg) {
      unsigned int w0 = mrow[reg][(t0 >> 5) + 0];
      unsigned int w1 = mrow[reg][(t0 >> 5) + 1];
#pragma unroll
      for (int ts = 0; ts < 4; ++ts) {
        unsigned int w = (ts < 2) ? w0 : w1;
        int bit = (ts & 1) * 16 + l;
        float keep = (float)((w >> bit) & 1u);
        float p = __expf(fminf(sf[ts][reg], 30.0f)) * keep;
        lpart[reg] += p;
        Ps[wave][quad * 4 + reg][ts * 16 + l] = (bf16_t)p;
      }
    }

    // P: C layout -> LDS -> A layout (per-wave buffer, in-order DS per wave)
    bf16x8 ap0 = *(const bf16x8*)&Ps[wave][l][quad * 8];
    bf16x8 ap1 = *(const bf16x8*)&Ps[wave][l][32 + quad * 8];
#pragma unroll
    for (int nt = 0; nt < 4; ++nt) {
      bf16x8 bv0 = *(const bf16x8*)&Vts[nt * 16 + l][quad * 8];
      bf16x8 bv1 = *(const bf16x8*)&Vts[nt * 16 + l][32 + quad * 8];
      o[nt] = mfma16(ap0, bv0, o[nt]);
      o[nt] = mfma16(ap1, bv1, o[nt]);
    }
  }

  // epilogue: reduce row sums, guarded divide, write [B*S, D] bf16
#pragma unroll
  for (int reg = 0; reg < 4; ++reg) {
    float rsum = lpart[reg];
#pragma unroll
    for (int m = 1; m < 16; m <<= 1) rsum += __shfl_xor(rsum, m);
    float inv = (rsum > 0.f) ? (1.f / rsum) : 0.f;
    int srow = qt * 64 + wave * 16 + quad * 4 + reg;
    bf16_t* op = out + (rb + srow) * D_ + ch;
#pragma unroll
    for (int nt = 0; nt < 4; ++nt)
      op[nt * 16 + l] = (bf16_t)(o[nt][reg] * inv);
  }
}

// ---------------------------------------------------------------------------
extern "C" void kernel_launch(void* const* d_in, const int* in_sizes, int n_in,
                              void* d_out, int out_size, void* d_ws, size_t ws_size,
                              hipStream_t stream) {
  const float* q_in = (const float*)d_in[0];
  const float* k_in = (const float*)d_in[1];
  const float* v_in = (const float*)d_in[2];
  const int* mask = (const int*)d_in[3];
  const float* Wq = (const float*)d_in[4];
  const float* Wk = (const float*)d_in[5];
  const float* Wv = (const float*)d_in[6];
  const float* Wu = (const float*)d_in[7];
  const float* bu = (const float*)d_in[8];
  float* outp = (float*)d_out;

  bf16_t* qx = (bf16_t*)d_ws;
  bf16_t* kx = qx + NX_;
  bf16_t* vx = kx + NX_;
  bf16_t* qb = vx + NX_;
  bf16_t* kb = qb + NX_;
  bf16_t* vb = kb + NX_;
  bf16_t* BTq = vb + NX_;
  bf16_t* BTk = BTq + D_ * D_;
  bf16_t* BTv = BTk + D_ * D_;
  bf16_t* BTu = BTv + D_ * D_;
  unsigned int* mb = (unsigned int*)(BTu + D_ * D_);
  bf16_t* ab = qx;  // qx dead after qkv gemm

  const float qkscale = 0.35355339059327373f;  // 1 / 64^0.25

  dim3 blk(256);
  cvt_x<<<dim3(2048, 3), blk, 0, stream>>>(q_in, k_in, v_in, qx, kx, vx);
  wtrans<<<dim3(16, 16, 4), blk, 0, stream>>>(Wq, Wk, Wv, Wu, BTq, BTk, BTv, BTu, qkscale);
  mask_pack<<<dim3(1024), blk, 0, stream>>>(mask, mb);
  gemm_bt<false><<<dim3(32, 8, 3), blk, 0, stream>>>(qx, kx, vx, BTq, BTk, BTv,
                                                     qb, kb, vb, nullptr);
  attn_kernel<<<dim3(S_ / 64, H_, B_), blk, 0, stream>>>(qb, kb, vb, mb, ab);
  gemm_bt<true><<<dim3(32, 8, 1), blk, 0, stream>>>(ab, ab, ab, BTu, BTu, BTu,
                                                    outp, outp, outp, bu);
}

// Round 7
// 298.519 us; speedup vs baseline: 1.3824x; 1.1255x over previous
//
#include <hip/hip_runtime.h>
#include <hip/hip_bf16.h>

// Problem: B=2, S=2048, D=1024, H=16, DK=64
// out = concat_heads(softmax(mask(qk^T))v) @ Wu + bu
// Inputs fp32 (mask int32), output fp32. Internal: bf16.
//
// R6 structure + R7 changes:
//   - XOR-swizzled LDS (c8' = c8 ^ (row&7)) for all global_load_lds tiles
//     -> kills the 16-way bank conflicts of the unpadded 64-pitch layout.
//   - attn: 128 q-rows/block (wave = 2 m-frags), K/V staged via swizzled
//     global_load_lds; V pre-transposed globally (vt_build) so no scalar
//     LDS scatter in the hot loop. P buffer padded to 72 (2-way, free).
//   - max-free finite softmax: p = exp(min(s,30)) * maskbit.

typedef __bf16 bf16_t;
typedef __attribute__((ext_vector_type(8))) __bf16 bf16x8;
typedef __attribute__((ext_vector_type(4))) float f32x4;
typedef unsigned int u32;

#define B_ 2
#define S_ 2048
#define D_ 1024
#define H_ 16
#define DK_ 64
#define NX_ (4096 * 1024)

static __device__ __forceinline__ f32x4 mfma16(bf16x8 a, bf16x8 b, f32x4 c) {
  return __builtin_amdgcn_mfma_f32_16x16x32_bf16(a, b, c, 0, 0, 0);
}

// async global->LDS, 16B/lane; lds base wave-uniform, slot = base + lane*16
static __device__ __forceinline__ void async16(const bf16_t* g, bf16_t* l) {
  __builtin_amdgcn_global_load_lds(
      (const __attribute__((address_space(1))) u32*)g,
      (__attribute__((address_space(3))) u32*)l, 16, 0, 0);
}

// ---------------------------------------------------------------------------
// q/k/v fp32 -> bf16
// ---------------------------------------------------------------------------
__global__ __launch_bounds__(256) void cvt_x(const float* __restrict__ q,
                                             const float* __restrict__ k,
                                             const float* __restrict__ v,
                                             bf16_t* __restrict__ qo,
                                             bf16_t* __restrict__ ko,
                                             bf16_t* __restrict__ vo) {
  const int z = blockIdx.y;
  const float* src = (z == 0) ? q : (z == 1) ? k : v;
  bf16_t* dst = (z == 0) ? qo : (z == 1) ? ko : vo;
  size_t i = ((size_t)blockIdx.x * 256 + threadIdx.x) * 8;
  float4 a = *(const float4*)(src + i);
  float4 b = *(const float4*)(src + i + 4);
  bf16x8 o;
  o[0] = (bf16_t)a.x; o[1] = (bf16_t)a.y; o[2] = (bf16_t)a.z; o[3] = (bf16_t)a.w;
  o[4] = (bf16_t)b.x; o[5] = (bf16_t)b.y; o[6] = (bf16_t)b.z; o[7] = (bf16_t)b.w;
  *(bf16x8*)(dst + i) = o;
}

// ---------------------------------------------------------------------------
// Weight transpose -> n-major bf16 BT[n][d]. qk scale folded for z<=1.
// ---------------------------------------------------------------------------
__global__ __launch_bounds__(256) void wtrans(
    const float* __restrict__ Wq, const float* __restrict__ Wk,
    const float* __restrict__ Wv, const float* __restrict__ Wu,
    bf16_t* __restrict__ Bq, bf16_t* __restrict__ Bk,
    bf16_t* __restrict__ Bv, bf16_t* __restrict__ Bu, float qkscale) {
  __shared__ __align__(16) bf16_t T[64][72];
  const int z = blockIdx.z;
  const float* W = (z == 0) ? Wq : (z == 1) ? Wk : (z == 2) ? Wv : Wu;
  bf16_t* BT = (z == 0) ? Bq : (z == 1) ? Bk : (z == 2) ? Bv : Bu;
  const float scale = (z <= 1) ? qkscale : 1.0f;
  const int d0 = blockIdx.x * 64, nt = blockIdx.y;
  const int tid = threadIdx.x;
  const int r = tid & 63, g = tid >> 6;

  const float* src = (z < 3)
      ? W + ((size_t)nt * D_ + d0 + r) * DK_ + g * 16
      : W + (size_t)(d0 + r) * D_ + nt * 64 + g * 16;
#pragma unroll
  for (int j = 0; j < 4; ++j) {
    float4 w4 = *(const float4*)(src + j * 4);
    T[g * 16 + j * 4 + 0][r] = (bf16_t)(w4.x * scale);
    T[g * 16 + j * 4 + 1][r] = (bf16_t)(w4.y * scale);
    T[g * 16 + j * 4 + 2][r] = (bf16_t)(w4.z * scale);
    T[g * 16 + j * 4 + 3][r] = (bf16_t)(w4.w * scale);
  }
  __syncthreads();
  const int orow = tid >> 3, seg = tid & 7;
#pragma unroll
  for (int p = 0; p < 2; ++p) {
    int rr = p * 32 + orow;
    *(bf16x8*)(BT + (size_t)(nt * 64 + rr) * D_ + d0 + seg * 8) =
        *(const bf16x8*)&T[rr][seg * 8];
  }
}

// ---------------------------------------------------------------------------
// V [4096][1024] bf16 -> Vt [1024][4096] bf16 (LDS-tiled transpose)
// ---------------------------------------------------------------------------
__global__ __launch_bounds__(256) void vt_build(const bf16_t* __restrict__ V,
                                                bf16_t* __restrict__ Vt) {
  __shared__ __align__(16) bf16_t T[64][72];
  const int r0 = blockIdx.x * 64;  // s-dim
  const int c0 = blockIdx.y * 64;  // d-dim
  const int tid = threadIdx.x;
#pragma unroll
  for (int it = 0; it < 2; ++it) {
    int t = tid + it * 256;
    int rr = t >> 3, cc = (t & 7) * 8;
    *(bf16x8*)&T[rr][cc] = *(const bf16x8*)(V + (size_t)(r0 + rr) * D_ + c0 + cc);
  }
  __syncthreads();
#pragma unroll
  for (int it = 0; it < 2; ++it) {
    int t = tid + it * 256;
    int cr = t >> 3, rc = (t & 7) * 8;  // out row = d, col group = s
    bf16x8 v;
#pragma unroll
    for (int j = 0; j < 8; ++j) v[j] = T[rc + j][cr];
    *(bf16x8*)(Vt + (size_t)(c0 + cr) * 4096 + r0 + rc) = v;
  }
}

// ---------------------------------------------------------------------------
// Pack mask [B,S,S] int32 -> bitfield (bit = mask != 0)
// ---------------------------------------------------------------------------
__global__ __launch_bounds__(256) void mask_pack(const int* __restrict__ mask,
                                                 unsigned int* __restrict__ bits) {
  int w = blockIdx.x * 256 + threadIdx.x;
  const int4* p = (const int4*)(mask + (size_t)w * 32);
  unsigned int v = 0;
#pragma unroll
  for (int i = 0; i < 8; ++i) {
    int4 m4 = p[i];
    v |= (m4.x != 0 ? 1u : 0u) << (i * 4 + 0);
    v |= (m4.y != 0 ? 1u : 0u) << (i * 4 + 1);
    v |= (m4.z != 0 ? 1u : 0u) << (i * 4 + 2);
    v |= (m4.w != 0 ? 1u : 0u) << (i * 4 + 3);
  }
  bits[w] = v;
}

// ---------------------------------------------------------------------------
// GEMM: C[4096,1024] = A @ BT^T, 128x128 tiles, BK=64, XOR-swizzled LDS.
// ---------------------------------------------------------------------------
template <bool BIAS_F32>
__global__ __launch_bounds__(256) void gemm_bt(
    const bf16_t* __restrict__ A0, const bf16_t* __restrict__ A1,
    const bf16_t* __restrict__ A2, const bf16_t* __restrict__ BT0,
    const bf16_t* __restrict__ BT1, const bf16_t* __restrict__ BT2,
    void* __restrict__ C0, void* __restrict__ C1, void* __restrict__ C2,
    const float* __restrict__ bias) {
  __shared__ __align__(16) bf16_t As[128 * 64];
  __shared__ __align__(16) bf16_t Bs[128 * 64];

  const int z = blockIdx.z;
  const bf16_t* A = (z == 0) ? A0 : (z == 1) ? A1 : A2;
  const bf16_t* BT = (z == 0) ? BT0 : (z == 1) ? BT1 : BT2;
  void* C = (z == 0) ? C0 : (z == 1) ? C1 : C2;

  const int tid = threadIdx.x;
  const int lane = tid & 63, wave = tid >> 6;
  const int l = lane & 15, quad = lane >> 4;
  const int wm = wave >> 1, wn = wave & 1;
  const int row0 = blockIdx.x * 128, col0 = blockIdx.y * 128;

  const int lr = lane >> 3;                 // row within 8-row staging group
  const int gc8 = (lane & 7) ^ lr;          // swizzled global 16B-group
  const int xl = l & 7;                     // read-side swizzle key

  f32x4 acc[4][4];
#pragma unroll
  for (int i = 0; i < 4; ++i)
#pragma unroll
    for (int j = 0; j < 4; ++j) acc[i][j] = {0.f, 0.f, 0.f, 0.f};

  for (int k0 = 0; k0 < 1024; k0 += 64) {
    __syncthreads();
#pragma unroll
    for (int c = 0; c < 4; ++c) {
      int r = wave * 32 + c * 8;  // wave-uniform
      async16(A + (size_t)(row0 + r + lr) * 1024 + k0 + gc8 * 8, As + r * 64);
      async16(BT + (size_t)(col0 + r + lr) * 1024 + k0 + gc8 * 8, Bs + r * 64);
    }
    __syncthreads();

#pragma unroll
    for (int kh = 0; kh < 2; ++kh) {
      bf16x8 af[4], bf[4];
#pragma unroll
      for (int f = 0; f < 4; ++f)
        af[f] = *(const bf16x8*)&As[(wm * 64 + f * 16 + l) * 64 +
                                    (((kh * 4 + quad) ^ xl) * 8)];
#pragma unroll
      for (int f = 0; f < 4; ++f)
        bf[f] = *(const bf16x8*)&Bs[(wn * 64 + f * 16 + l) * 64 +
                                    (((kh * 4 + quad) ^ xl) * 8)];
#pragma unroll
      for (int fm = 0; fm < 4; ++fm)
#pragma unroll
        for (int fn = 0; fn < 4; ++fn)
          acc[fm][fn] = mfma16(af[fm], bf[fn], acc[fm][fn]);
    }
  }

#pragma unroll
  for (int fm = 0; fm < 4; ++fm)
#pragma unroll
    for (int fn = 0; fn < 4; ++fn)
#pragma unroll
      for (int reg = 0; reg < 4; ++reg) {
        int row = row0 + wm * 64 + fm * 16 + quad * 4 + reg;
        int col = col0 + wn * 64 + fn * 16 + l;
        if (BIAS_F32)
          ((float*)C)[(size_t)row * 1024 + col] = acc[fm][fn][reg] + bias[col];
        else
          ((bf16_t*)C)[(size_t)row * 1024 + col] = (bf16_t)acc[fm][fn][reg];
      }
}

// ---------------------------------------------------------------------------
// Flash attention. Block = (128 q-rows, head, batch); 4 waves x 32 q-rows
// (2 m-frags). K from [B*S,D]; V from pre-transposed Vt [D][B*S]. Swizzled
// global_load_lds staging; P buffer padded (pitch 72).
// ---------------------------------------------------------------------------
__global__ __launch_bounds__(256) void attn_kernel(
    const bf16_t* __restrict__ Qx, const bf16_t* __restrict__ Kx,
    const bf16_t* __restrict__ Vt, const unsigned int* __restrict__ mbits,
    bf16_t* __restrict__ out) {
  __shared__ __align__(16) bf16_t Ks[64 * 64];     // [t][c] swizzled
  __shared__ __align__(16) bf16_t Vts[64 * 64];    // [c][t] swizzled
  __shared__ __align__(16) bf16_t Ps[4][32][72];   // per-wave P, padded

  const int tid = threadIdx.x;
  const int lane = tid & 63, wave = tid >> 6;
  const int l = lane & 15, quad = lane >> 4;
  const int qt = blockIdx.x, h = blockIdx.y, b = blockIdx.z;
  const int ch = h * 64;
  const size_t rb = (size_t)b * S_;
  const int q0 = qt * 128 + wave * 32;

  const int lr = lane >> 3;
  const int gc8 = (lane & 7) ^ lr;
  const int xl = l & 7;

  // Q fragments: 2 m-frags x (2 k-halves)
  bf16x8 aq[2][2];
#pragma unroll
  for (int mf = 0; mf < 2; ++mf) {
    const bf16_t* qp = Qx + (rb + q0 + mf * 16 + l) * D_ + ch;
    aq[mf][0] = *(const bf16x8*)(qp + quad * 8);
    aq[mf][1] = *(const bf16x8*)(qp + 32 + quad * 8);
  }

  const f32x4 zero = {0.f, 0.f, 0.f, 0.f};
  f32x4 o[2][4];
  float lpart[2][4];
#pragma unroll
  for (int mf = 0; mf < 2; ++mf)
#pragma unroll
    for (int i = 0; i < 4; ++i) { o[mf][i] = zero; lpart[mf][i] = 0.f; }

  for (int t0 = 0; t0 < S_; t0 += 64) {
    __syncthreads();
    // stage K tile [t][c] and Vt tile [c][t], swizzled, 2 issues each
#pragma unroll
    for (int it = 0; it < 2; ++it) {
      int r0 = it * 32 + wave * 8;  // wave-uniform
      async16(Kx + (rb + t0 + r0 + lr) * D_ + ch + gc8 * 8, Ks + r0 * 64);
      async16(Vt + (size_t)(ch + r0 + lr) * 4096 + rb + t0 + gc8 * 8,
              Vts + r0 * 64);
    }
    __syncthreads();

    // scores: per m-frag 16x64, C layout (row=quad*4+reg, col=ts*16+l)
    f32x4 sf[2][4];
#pragma unroll
    for (int ts = 0; ts < 4; ++ts) {
      int rK = (ts * 16 + l) * 64;
      bf16x8 bk0 = *(const bf16x8*)&Ks[rK + ((quad ^ xl) * 8)];
      bf16x8 bk1 = *(const bf16x8*)&Ks[rK + (((4 + quad) ^ xl) * 8)];
#pragma unroll
      for (int mf = 0; mf < 2; ++mf) {
        f32x4 c = mfma16(aq[mf][0], bk0, zero);
        sf[mf][ts] = mfma16(aq[mf][1], bk1, c);
      }
    }

    // p = exp(min(s,30)) * maskbit — finite by construction
#pragma unroll
    for (int mf = 0; mf < 2; ++mf)
#pragma unroll
      for (int reg = 0; reg < 4; ++reg) {
        int srow = q0 + mf * 16 + quad * 4 + reg;
        const u32* mp = mbits + (size_t)(b * S_ + srow) * (S_ / 32) + (t0 >> 5);
        u32 w0 = mp[0], w1 = mp[1];
#pragma unroll
        for (int ts = 0; ts < 4; ++ts) {
          u32 w = (ts < 2) ? w0 : w1;
          int bit = (ts & 1) * 16 + l;
          float keep = (float)((w >> bit) & 1u);
          float p = __expf(fminf(sf[mf][ts][reg], 30.0f)) * keep;
          lpart[mf][reg] += p;
          Ps[wave][mf * 16 + quad * 4 + reg][ts * 16 + l] = (bf16_t)p;
        }
      }

    // P: C layout -> LDS -> A layout (per-wave, in-order DS per wave)
    bf16x8 ap[2][2];
#pragma unroll
    for (int mf = 0; mf < 2; ++mf) {
      ap[mf][0] = *(const bf16x8*)&Ps[wave][mf * 16 + l][quad * 8];
      ap[mf][1] = *(const bf16x8*)&Ps[wave][mf * 16 + l][32 + quad * 8];
    }
#pragma unroll
    for (int nt = 0; nt < 4; ++nt) {
      int rV = (nt * 16 + l) * 64;
      bf16x8 bv0 = *(const bf16x8*)&Vts[rV + ((quad ^ xl) * 8)];
      bf16x8 bv1 = *(const bf16x8*)&Vts[rV + (((4 + quad) ^ xl) * 8)];
#pragma unroll
      for (int mf = 0; mf < 2; ++mf) {
        o[mf][nt] = mfma16(ap[mf][0], bv0, o[mf][nt]);
        o[mf][nt] = mfma16(ap[mf][1], bv1, o[mf][nt]);
      }
    }
  }

  // epilogue: reduce row sums over 16 lanes, guarded divide, write bf16
#pragma unroll
  for (int mf = 0; mf < 2; ++mf)
#pragma unroll
    for (int reg = 0; reg < 4; ++reg) {
      float rsum = lpart[mf][reg];
#pragma unroll
      for (int m = 1; m < 16; m <<= 1) rsum += __shfl_xor(rsum, m);
      float inv = (rsum > 0.f) ? (1.f / rsum) : 0.f;
      int srow = q0 + mf * 16 + quad * 4 + reg;
      bf16_t* op = out + (rb + srow) * D_ + ch;
#pragma unroll
      for (int nt = 0; nt < 4; ++nt)
        op[nt * 16 + l] = (bf16_t)(o[mf][nt][reg] * inv);
    }
}

// ---------------------------------------------------------------------------
extern "C" void kernel_launch(void* const* d_in, const int* in_sizes, int n_in,
                              void* d_out, int out_size, void* d_ws, size_t ws_size,
                              hipStream_t stream) {
  const float* q_in = (const float*)d_in[0];
  const float* k_in = (const float*)d_in[1];
  const float* v_in = (const float*)d_in[2];
  const int* mask = (const int*)d_in[3];
  const float* Wq = (const float*)d_in[4];
  const float* Wk = (const float*)d_in[5];
  const float* Wv = (const float*)d_in[6];
  const float* Wu = (const float*)d_in[7];
  const float* bu = (const float*)d_in[8];
  float* outp = (float*)d_out;

  bf16_t* qx = (bf16_t*)d_ws;
  bf16_t* kx = qx + NX_;
  bf16_t* vx = kx + NX_;
  bf16_t* qb = vx + NX_;
  bf16_t* kb = qb + NX_;
  bf16_t* vb = kb + NX_;
  bf16_t* BTq = vb + NX_;
  bf16_t* BTk = BTq + D_ * D_;
  bf16_t* BTv = BTk + D_ * D_;
  bf16_t* BTu = BTv + D_ * D_;
  unsigned int* mb = (unsigned int*)(BTu + D_ * D_);
  bf16_t* ab = qx;   // qx dead after qkv gemm
  bf16_t* vtb = kx;  // kx dead after qkv gemm

  const float qkscale = 0.35355339059327373f;  // 1 / 64^0.25

  dim3 blk(256);
  cvt_x<<<dim3(2048, 3), blk, 0, stream>>>(q_in, k_in, v_in, qx, kx, vx);
  wtrans<<<dim3(16, 16, 4), blk, 0, stream>>>(Wq, Wk, Wv, Wu, BTq, BTk, BTv, BTu, qkscale);
  mask_pack<<<dim3(1024), blk, 0, stream>>>(mask, mb);
  gemm_bt<false><<<dim3(32, 8, 3), blk, 0, stream>>>(qx, kx, vx, BTq, BTk, BTv,
                                                     qb, kb, vb, nullptr);
  vt_build<<<dim3(64, 16), blk, 0, stream>>>(vb, vtb);
  attn_kernel<<<dim3(S_ / 128, H_, B_), blk, 0, stream>>>(qb, kb, vtb, mb, ab);
  gemm_bt<true><<<dim3(32, 8, 1), blk, 0, stream>>>(ab, ab, ab, BTu, BTu, BTu,
                                                    outp, outp, outp, bu);
}

// Round 8
// 287.251 us; speedup vs baseline: 1.4367x; 1.0392x over previous
//
#include <hip/hip_runtime.h>
#include <hip/hip_bf16.h>

// Problem: B=2, S=2048, D=1024, H=16, DK=64
// out = concat_heads(softmax(mask(qk^T))v) @ Wu + bu
// Inputs fp32 (mask int32), output fp32. Internal: bf16.
//
// R8: transposed-score flash attention. S' = K.Q^T so the C-layout gives
// each lane 4 consecutive t for fixed q -> P written [q][t] with b64 stores,
// PV = P.V^T with A=P (b128 reads), O in C-layout written directly.
// 64-q blocks of 2 waves -> grid 1024 = 4 blocks/CU for barrier overlap.
// Out-proj GEMM: 64x128 tiles -> 512 blocks. Softmax stays max-free finite:
// p = exp(min(s,30)) * maskbit.

typedef __bf16 bf16_t;
typedef __attribute__((ext_vector_type(4))) __bf16 bf16x4;
typedef __attribute__((ext_vector_type(8))) __bf16 bf16x8;
typedef __attribute__((ext_vector_type(4))) float f32x4;
typedef unsigned int u32;

#define B_ 2
#define S_ 2048
#define D_ 1024
#define H_ 16
#define DK_ 64
#define NX_ (4096 * 1024)

static __device__ __forceinline__ f32x4 mfma16(bf16x8 a, bf16x8 b, f32x4 c) {
  return __builtin_amdgcn_mfma_f32_16x16x32_bf16(a, b, c, 0, 0, 0);
}

// async global->LDS, 16B/lane; lds base wave-uniform, slot = base + lane*16
static __device__ __forceinline__ void async16(const bf16_t* g, bf16_t* l) {
  __builtin_amdgcn_global_load_lds(
      (const __attribute__((address_space(1))) u32*)g,
      (__attribute__((address_space(3))) u32*)l, 16, 0, 0);
}

// ---------------------------------------------------------------------------
// q/k/v fp32 -> bf16
// ---------------------------------------------------------------------------
__global__ __launch_bounds__(256) void cvt_x(const float* __restrict__ q,
                                             const float* __restrict__ k,
                                             const float* __restrict__ v,
                                             bf16_t* __restrict__ qo,
                                             bf16_t* __restrict__ ko,
                                             bf16_t* __restrict__ vo) {
  const int z = blockIdx.y;
  const float* src = (z == 0) ? q : (z == 1) ? k : v;
  bf16_t* dst = (z == 0) ? qo : (z == 1) ? ko : vo;
  size_t i = ((size_t)blockIdx.x * 256 + threadIdx.x) * 8;
  float4 a = *(const float4*)(src + i);
  float4 b = *(const float4*)(src + i + 4);
  bf16x8 o;
  o[0] = (bf16_t)a.x; o[1] = (bf16_t)a.y; o[2] = (bf16_t)a.z; o[3] = (bf16_t)a.w;
  o[4] = (bf16_t)b.x; o[5] = (bf16_t)b.y; o[6] = (bf16_t)b.z; o[7] = (bf16_t)b.w;
  *(bf16x8*)(dst + i) = o;
}

// ---------------------------------------------------------------------------
// Weight transpose -> n-major bf16 BT[n][d]. qk scale folded for z<=1.
// ---------------------------------------------------------------------------
__global__ __launch_bounds__(256) void wtrans(
    const float* __restrict__ Wq, const float* __restrict__ Wk,
    const float* __restrict__ Wv, const float* __restrict__ Wu,
    bf16_t* __restrict__ Bq, bf16_t* __restrict__ Bk,
    bf16_t* __restrict__ Bv, bf16_t* __restrict__ Bu, float qkscale) {
  __shared__ __align__(16) bf16_t T[64][72];
  const int z = blockIdx.z;
  const float* W = (z == 0) ? Wq : (z == 1) ? Wk : (z == 2) ? Wv : Wu;
  bf16_t* BT = (z == 0) ? Bq : (z == 1) ? Bk : (z == 2) ? Bv : Bu;
  const float scale = (z <= 1) ? qkscale : 1.0f;
  const int d0 = blockIdx.x * 64, nt = blockIdx.y;
  const int tid = threadIdx.x;
  const int r = tid & 63, g = tid >> 6;

  const float* src = (z < 3)
      ? W + ((size_t)nt * D_ + d0 + r) * DK_ + g * 16
      : W + (size_t)(d0 + r) * D_ + nt * 64 + g * 16;
#pragma unroll
  for (int j = 0; j < 4; ++j) {
    float4 w4 = *(const float4*)(src + j * 4);
    T[g * 16 + j * 4 + 0][r] = (bf16_t)(w4.x * scale);
    T[g * 16 + j * 4 + 1][r] = (bf16_t)(w4.y * scale);
    T[g * 16 + j * 4 + 2][r] = (bf16_t)(w4.z * scale);
    T[g * 16 + j * 4 + 3][r] = (bf16_t)(w4.w * scale);
  }
  __syncthreads();
  const int orow = tid >> 3, seg = tid & 7;
#pragma unroll
  for (int p = 0; p < 2; ++p) {
    int rr = p * 32 + orow;
    *(bf16x8*)(BT + (size_t)(nt * 64 + rr) * D_ + d0 + seg * 8) =
        *(const bf16x8*)&T[rr][seg * 8];
  }
}

// ---------------------------------------------------------------------------
// V [4096][1024] bf16 -> Vt [1024][4096] bf16 (LDS-tiled transpose)
// ---------------------------------------------------------------------------
__global__ __launch_bounds__(256) void vt_build(const bf16_t* __restrict__ V,
                                                bf16_t* __restrict__ Vt) {
  __shared__ __align__(16) bf16_t T[64][72];
  const int r0 = blockIdx.x * 64;  // s-dim
  const int c0 = blockIdx.y * 64;  // d-dim
  const int tid = threadIdx.x;
#pragma unroll
  for (int it = 0; it < 2; ++it) {
    int t = tid + it * 256;
    int rr = t >> 3, cc = (t & 7) * 8;
    *(bf16x8*)&T[rr][cc] = *(const bf16x8*)(V + (size_t)(r0 + rr) * D_ + c0 + cc);
  }
  __syncthreads();
#pragma unroll
  for (int it = 0; it < 2; ++it) {
    int t = tid + it * 256;
    int cr = t >> 3, rc = (t & 7) * 8;
    bf16x8 v;
#pragma unroll
    for (int j = 0; j < 8; ++j) v[j] = T[rc + j][cr];
    *(bf16x8*)(Vt + (size_t)(c0 + cr) * 4096 + r0 + rc) = v;
  }
}

// ---------------------------------------------------------------------------
// Pack mask [B,S,S] int32 -> bitfield (bit = mask != 0)
// ---------------------------------------------------------------------------
__global__ __launch_bounds__(256) void mask_pack(const int* __restrict__ mask,
                                                 unsigned int* __restrict__ bits) {
  int w = blockIdx.x * 256 + threadIdx.x;
  const int4* p = (const int4*)(mask + (size_t)w * 32);
  unsigned int v = 0;
#pragma unroll
  for (int i = 0; i < 8; ++i) {
    int4 m4 = p[i];
    v |= (m4.x != 0 ? 1u : 0u) << (i * 4 + 0);
    v |= (m4.y != 0 ? 1u : 0u) << (i * 4 + 1);
    v |= (m4.z != 0 ? 1u : 0u) << (i * 4 + 2);
    v |= (m4.w != 0 ? 1u : 0u) << (i * 4 + 3);
  }
  bits[w] = v;
}

// ---------------------------------------------------------------------------
// GEMM 128x128: C[4096,1024] = A @ BT^T, BK=64, XOR-swizzled LDS. (qkv, z=3)
// ---------------------------------------------------------------------------
__global__ __launch_bounds__(256) void gemm_bt(
    const bf16_t* __restrict__ A0, const bf16_t* __restrict__ A1,
    const bf16_t* __restrict__ A2, const bf16_t* __restrict__ BT0,
    const bf16_t* __restrict__ BT1, const bf16_t* __restrict__ BT2,
    bf16_t* __restrict__ C0, bf16_t* __restrict__ C1, bf16_t* __restrict__ C2) {
  __shared__ __align__(16) bf16_t As[128 * 64];
  __shared__ __align__(16) bf16_t Bs[128 * 64];

  const int z = blockIdx.z;
  const bf16_t* A = (z == 0) ? A0 : (z == 1) ? A1 : A2;
  const bf16_t* BT = (z == 0) ? BT0 : (z == 1) ? BT1 : BT2;
  bf16_t* C = (z == 0) ? C0 : (z == 1) ? C1 : C2;

  const int tid = threadIdx.x;
  const int lane = tid & 63, wave = tid >> 6;
  const int l = lane & 15, quad = lane >> 4;
  const int wm = wave >> 1, wn = wave & 1;
  const int row0 = blockIdx.x * 128, col0 = blockIdx.y * 128;

  const int lr = lane >> 3;
  const int gc8 = (lane & 7) ^ lr;
  const int xl = l & 7;

  f32x4 acc[4][4];
#pragma unroll
  for (int i = 0; i < 4; ++i)
#pragma unroll
    for (int j = 0; j < 4; ++j) acc[i][j] = {0.f, 0.f, 0.f, 0.f};

  for (int k0 = 0; k0 < 1024; k0 += 64) {
    __syncthreads();
#pragma unroll
    for (int c = 0; c < 4; ++c) {
      int r = wave * 32 + c * 8;
      async16(A + (size_t)(row0 + r + lr) * 1024 + k0 + gc8 * 8, As + r * 64);
      async16(BT + (size_t)(col0 + r + lr) * 1024 + k0 + gc8 * 8, Bs + r * 64);
    }
    __syncthreads();

#pragma unroll
    for (int kh = 0; kh < 2; ++kh) {
      bf16x8 af[4], bf[4];
#pragma unroll
      for (int f = 0; f < 4; ++f)
        af[f] = *(const bf16x8*)&As[(wm * 64 + f * 16 + l) * 64 +
                                    (((kh * 4 + quad) ^ xl) * 8)];
#pragma unroll
      for (int f = 0; f < 4; ++f)
        bf[f] = *(const bf16x8*)&Bs[(wn * 64 + f * 16 + l) * 64 +
                                    (((kh * 4 + quad) ^ xl) * 8)];
#pragma unroll
      for (int fm = 0; fm < 4; ++fm)
#pragma unroll
        for (int fn = 0; fn < 4; ++fn)
          acc[fm][fn] = mfma16(af[fm], bf[fn], acc[fm][fn]);
    }
  }

#pragma unroll
  for (int fm = 0; fm < 4; ++fm)
#pragma unroll
    for (int fn = 0; fn < 4; ++fn)
#pragma unroll
      for (int reg = 0; reg < 4; ++reg) {
        int row = row0 + wm * 64 + fm * 16 + quad * 4 + reg;
        int col = col0 + wn * 64 + fn * 16 + l;
        C[(size_t)row * 1024 + col] = (bf16_t)acc[fm][fn][reg];
      }
}

// ---------------------------------------------------------------------------
// GEMM 64x128 (out-proj): out = A @ BT^T + bias, fp32 out. Grid (64,8) = 512
// blocks -> 2/CU. 4 waves side by side (32 cols each), 4 m-frags per wave.
// ---------------------------------------------------------------------------
__global__ __launch_bounds__(256) void gemm_bt64(
    const bf16_t* __restrict__ A, const bf16_t* __restrict__ BT,
    float* __restrict__ C, const float* __restrict__ bias) {
  __shared__ __align__(16) bf16_t As[64 * 64];
  __shared__ __align__(16) bf16_t Bs[128 * 64];

  const int tid = threadIdx.x;
  const int lane = tid & 63, wave = tid >> 6;
  const int l = lane & 15, quad = lane >> 4;
  const int row0 = blockIdx.x * 64, col0 = blockIdx.y * 128;

  const int lr = lane >> 3;
  const int gc8 = (lane & 7) ^ lr;
  const int xl = l & 7;

  f32x4 acc[4][2];
#pragma unroll
  for (int i = 0; i < 4; ++i)
#pragma unroll
    for (int j = 0; j < 2; ++j) acc[i][j] = {0.f, 0.f, 0.f, 0.f};

  for (int k0 = 0; k0 < 1024; k0 += 64) {
    __syncthreads();
#pragma unroll
    for (int c = 0; c < 2; ++c) {
      int r = wave * 16 + c * 8;
      async16(A + (size_t)(row0 + r + lr) * 1024 + k0 + gc8 * 8, As + r * 64);
    }
#pragma unroll
    for (int c = 0; c < 4; ++c) {
      int r = wave * 32 + c * 8;
      async16(BT + (size_t)(col0 + r + lr) * 1024 + k0 + gc8 * 8, Bs + r * 64);
    }
    __syncthreads();

#pragma unroll
    for (int kh = 0; kh < 2; ++kh) {
      bf16x8 af[4], bf[2];
#pragma unroll
      for (int f = 0; f < 4; ++f)
        af[f] = *(const bf16x8*)&As[(f * 16 + l) * 64 +
                                    (((kh * 4 + quad) ^ xl) * 8)];
#pragma unroll
      for (int f = 0; f < 2; ++f)
        bf[f] = *(const bf16x8*)&Bs[(wave * 32 + f * 16 + l) * 64 +
                                    (((kh * 4 + quad) ^ xl) * 8)];
#pragma unroll
      for (int fm = 0; fm < 4; ++fm)
#pragma unroll
        for (int fn = 0; fn < 2; ++fn)
          acc[fm][fn] = mfma16(af[fm], bf[fn], acc[fm][fn]);
    }
  }

#pragma unroll
  for (int fm = 0; fm < 4; ++fm)
#pragma unroll
    for (int fn = 0; fn < 2; ++fn)
#pragma unroll
      for (int reg = 0; reg < 4; ++reg) {
        int row = row0 + fm * 16 + quad * 4 + reg;
        int col = col0 + wave * 32 + fn * 16 + l;
        C[(size_t)row * 1024 + col] = acc[fm][fn][reg] + bias[col];
      }
}

// ---------------------------------------------------------------------------
// Flash attention, transposed-score form. Block = 64 q (2 waves x 32 q),
// 64-wide t tiles. S'[t][q] = K.Q^T -> lane holds 4 consecutive t per q ->
// P stored [q][t] via b64, PV = P.V^T (A=P b128, B=Vts), O in C-layout.
// ---------------------------------------------------------------------------
__global__ __launch_bounds__(128) void attn_kernel(
    const bf16_t* __restrict__ Qx, const bf16_t* __restrict__ Kx,
    const bf16_t* __restrict__ Vt, const unsigned int* __restrict__ mbits,
    bf16_t* __restrict__ out) {
  __shared__ __align__(16) bf16_t Ks[64 * 64];    // [t][dk] swizzled
  __shared__ __align__(16) bf16_t Vts[64 * 64];   // [d][t]  swizzled
  __shared__ __align__(16) bf16_t Ps[2][32][72];  // per-wave P [q][t], pitch 72

  const int tid = threadIdx.x;
  const int lane = tid & 63, wave = tid >> 6;  // 2 waves
  const int l = lane & 15, quad = lane >> 4;
  const int qt = blockIdx.x, h = blockIdx.y, b = blockIdx.z;
  const int ch = h * 64;
  const size_t rb = (size_t)b * S_;
  const int q0 = qt * 64 + wave * 32;

  const int lr = lane >> 3;
  const int gc8 = (lane & 7) ^ lr;
  const int xl = l & 7;

  // Q B-frags: bq[mf][kc], B[n=q=l][k=dk=kc*32+quad*8+j]
  bf16x8 bq[2][2];
#pragma unroll
  for (int mf = 0; mf < 2; ++mf) {
    const bf16_t* qp = Qx + (rb + q0 + mf * 16 + l) * D_ + ch;
    bq[mf][0] = *(const bf16x8*)(qp + quad * 8);
    bq[mf][1] = *(const bf16x8*)(qp + 32 + quad * 8);
  }

  const f32x4 zero = {0.f, 0.f, 0.f, 0.f};
  f32x4 o[2][4];  // O[q][d]: [mf][nt], C-layout (row=q_local, col=d)
  float lsum[2] = {0.f, 0.f};
#pragma unroll
  for (int mf = 0; mf < 2; ++mf)
#pragma unroll
    for (int nt = 0; nt < 4; ++nt) o[mf][nt] = zero;

  const u32* mrow[2];
#pragma unroll
  for (int mf = 0; mf < 2; ++mf)
    mrow[mf] = mbits + (size_t)(b * S_ + q0 + mf * 16 + l) * (S_ / 32);

  for (int t0 = 0; t0 < S_; t0 += 64) {
    __syncthreads();
    // stage K [t][dk] and V^T [d][t], swizzled; 4 issue-rounds per wave each
#pragma unroll
    for (int it = 0; it < 4; ++it) {
      int r0 = it * 16 + wave * 8;
      async16(Kx + (rb + t0 + r0 + lr) * D_ + ch + gc8 * 8, Ks + r0 * 64);
      async16(Vt + (size_t)(ch + r0 + lr) * 4096 + rb + t0 + gc8 * 8,
              Vts + r0 * 64);
    }
    __syncthreads();

    // S' = K.Q^T per (mf, ts): D[m=t=quad*4+reg][n=q=l]
#pragma unroll
    for (int mf = 0; mf < 2; ++mf) {
      u32 mw0 = mrow[mf][(t0 >> 5)];
      u32 mw1 = mrow[mf][(t0 >> 5) + 1];
#pragma unroll
      for (int ts = 0; ts < 4; ++ts) {
        int rK = (ts * 16 + l) * 64;
        bf16x8 ak0 = *(const bf16x8*)&Ks[rK + ((quad ^ xl) * 8)];
        bf16x8 ak1 = *(const bf16x8*)&Ks[rK + (((4 + quad) ^ xl) * 8)];
        f32x4 s = mfma16(ak0, bq[mf][0], zero);
        s = mfma16(ak1, bq[mf][1], s);

        u32 mw = (ts < 2) ? mw0 : mw1;
        u32 nib = (mw >> ((ts & 1) * 16 + quad * 4)) & 0xFu;
        bf16x4 pv;
#pragma unroll
        for (int reg = 0; reg < 4; ++reg) {
          float e = __expf(fminf(s[reg], 30.0f));
          float p = ((nib >> reg) & 1u) ? e : 0.0f;
          lsum[mf] += p;
          pv[reg] = (bf16_t)p;
        }
        // P[q=mf*16+l][t = ts*16+quad*4 .. +3], contiguous 8B
        *(bf16x4*)&Ps[wave][mf * 16 + l][ts * 16 + quad * 4] = pv;
      }
    }

    // PV: O[q][d] += P.V^T  (A=P from Ps, B=Vts; per-wave buf, in-order DS)
    bf16x8 ap[2][2];
#pragma unroll
    for (int mf = 0; mf < 2; ++mf) {
      ap[mf][0] = *(const bf16x8*)&Ps[wave][mf * 16 + l][quad * 8];
      ap[mf][1] = *(const bf16x8*)&Ps[wave][mf * 16 + l][32 + quad * 8];
    }
#pragma unroll
    for (int nt = 0; nt < 4; ++nt) {
      int rV = (nt * 16 + l) * 64;
      bf16x8 bv0 = *(const bf16x8*)&Vts[rV + ((quad ^ xl) * 8)];
      bf16x8 bv1 = *(const bf16x8*)&Vts[rV + (((4 + quad) ^ xl) * 8)];
#pragma unroll
      for (int mf = 0; mf < 2; ++mf) {
        o[mf][nt] = mfma16(ap[mf][0], bv0, o[mf][nt]);
        o[mf][nt] = mfma16(ap[mf][1], bv1, o[mf][nt]);
      }
    }
  }

  // epilogue: per-lane row sum (q=l), reduce across quads, broadcast inv to
  // C-layout rows, write [B*S, D] bf16
#pragma unroll
  for (int mf = 0; mf < 2; ++mf) {
    float rsum = lsum[mf];
    rsum += __shfl_xor(rsum, 16);
    rsum += __shfl_xor(rsum, 32);
    float inv = (rsum > 0.f) ? (1.f / rsum) : 0.f;
    float invr[4];
#pragma unroll
    for (int reg = 0; reg < 4; ++reg) invr[reg] = __shfl(inv, quad * 4 + reg);
#pragma unroll
    for (int reg = 0; reg < 4; ++reg) {
      int srow = q0 + mf * 16 + quad * 4 + reg;
      bf16_t* op = out + (rb + srow) * D_ + ch;
#pragma unroll
      for (int nt = 0; nt < 4; ++nt)
        op[nt * 16 + l] = (bf16_t)(o[mf][nt][reg] * invr[reg]);
    }
  }
}

// ---------------------------------------------------------------------------
extern "C" void kernel_launch(void* const* d_in, const int* in_sizes, int n_in,
                              void* d_out, int out_size, void* d_ws, size_t ws_size,
                              hipStream_t stream) {
  const float* q_in = (const float*)d_in[0];
  const float* k_in = (const float*)d_in[1];
  const float* v_in = (const float*)d_in[2];
  const int* mask = (const int*)d_in[3];
  const float* Wq = (const float*)d_in[4];
  const float* Wk = (const float*)d_in[5];
  const float* Wv = (const float*)d_in[6];
  const float* Wu = (const float*)d_in[7];
  const float* bu = (const float*)d_in[8];
  float* outp = (float*)d_out;

  bf16_t* qx = (bf16_t*)d_ws;
  bf16_t* kx = qx + NX_;
  bf16_t* vx = kx + NX_;
  bf16_t* qb = vx + NX_;
  bf16_t* kb = qb + NX_;
  bf16_t* vb = kb + NX_;
  bf16_t* BTq = vb + NX_;
  bf16_t* BTk = BTq + D_ * D_;
  bf16_t* BTv = BTk + D_ * D_;
  bf16_t* BTu = BTv + D_ * D_;
  unsigned int* mb = (unsigned int*)(BTu + D_ * D_);
  bf16_t* ab = qx;   // qx dead after qkv gemm
  bf16_t* vtb = kx;  // kx dead after qkv gemm

  const float qkscale = 0.35355339059327373f;  // 1 / 64^0.25

  dim3 blk(256);
  cvt_x<<<dim3(2048, 3), blk, 0, stream>>>(q_in, k_in, v_in, qx, kx, vx);
  wtrans<<<dim3(16, 16, 4), blk, 0, stream>>>(Wq, Wk, Wv, Wu, BTq, BTk, BTv, BTu, qkscale);
  mask_pack<<<dim3(1024), blk, 0, stream>>>(mask, mb);
  gemm_bt<<<dim3(32, 8, 3), blk, 0, stream>>>(qx, kx, vx, BTq, BTk, BTv,
                                              qb, kb, vb);
  vt_build<<<dim3(64, 16), blk, 0, stream>>>(vb, vtb);
  attn_kernel<<<dim3(S_ / 64, H_, B_), dim3(128), 0, stream>>>(qb, kb, vtb, mb, ab);
  gemm_bt64<<<dim3(64, 8), blk, 0, stream>>>(ab, BTu, outp, bu);
}